// Round 11
// baseline (568.127 us; speedup 1.0000x reference)
//
#include <hip/hip_runtime.h>

typedef unsigned short u16;
typedef unsigned int u32;
typedef __bf16 bf16x8 __attribute__((ext_vector_type(8)));
typedef float floatx4 __attribute__((ext_vector_type(4)));

#define HID 1024
#define BATCH 64
#define SEQ 256
#define INDIM 128
#define OUTDIM 128
#define MROWS (BATCH*SEQ)   // 16384
#define CUMP 140            // padded LDS row stride (u16) for the cumsum epilogue

__device__ __forceinline__ float b2f(u16 u) {
    union { u32 u; float f; } v; v.u = ((u32)u) << 16; return v.f;
}
__device__ __forceinline__ u16 f2b(float f) {
    union { float f; u32 u; } v; v.f = f;
    u32 x = v.u;
    x += 0x7fffu + ((x >> 16) & 1u);
    return (u16)(x >> 16);
}
__device__ __forceinline__ float sigm(float x) { return 1.f / (1.f + __expf(-x)); }
__device__ __forceinline__ float tanh_f(float x) { return 2.f / (1.f + __expf(-2.f * x)) - 1.f; }

__device__ __forceinline__ void gld16(const u16* g, u16* l) {
    __builtin_amdgcn_global_load_lds(
        (const __attribute__((address_space(1))) void*)g,
        (__attribute__((address_space(3))) void*)l, 16, 0, 0);
}

// raw barrier (no vmcnt drain) + compiler memory fences
__device__ __forceinline__ void bar_sync() {
    asm volatile("" ::: "memory");
    __builtin_amdgcn_s_barrier();
    asm volatile("" ::: "memory");
}
// counted vmcnt wait + barrier: loads stay in flight across the barrier
template <int N>
__device__ __forceinline__ void vm_bar() {
    asm volatile("s_waitcnt vmcnt(%0)" :: "n"(N) : "memory");
    __builtin_amdgcn_s_barrier();
    asm volatile("" ::: "memory");
}

// ---------------------------------------------------------------------------
// inline wave-ballot dtype self-detect (probe = l0_Wh / fc_W, uniform ±1/32)
// ---------------------------------------------------------------------------
__device__ __forceinline__ int is_fp32(const u16* probe, int tid) {
    const int lane = tid & 63;
    const int e = (probe[lane * 7] >> 7) & 0xff;
    return __ballot(e >= 127) != 0ULL;
}

// ---------------------------------------------------------------------------
// MERGED prep kernel: z = 0..9 transpose 10 weight matrices [R,C]->[C,R];
// z = 10..17 convert 8 tensors (x + 6 bias vectors + Win0) to clean bf16.
// ---------------------------------------------------------------------------
struct PrepList {
    const void* ts[10]; u16* td[10]; int tR[10]; int tC[10]; long toff[10];
    const void* cs[8];  u16* cd[8];  int cn[8];
};

__global__ void prep18(PrepList P, const u16* __restrict__ probe) {
    const int tid  = threadIdx.x;                 // 256
    const int fp32 = is_fp32(probe, tid);         // before any divergence
    const int z = blockIdx.z;
    if (z < 10) {
        // ---- transpose path ----
        const int tx = tid & 31, ty = tid >> 5;   // (32,8)
        const void* src = P.ts[z];
        u16*        dst = P.td[z];
        const int R  = P.tR[z];
        const int Cc = P.tC[z];
        const long zo = P.toff[z];
        const int tr = blockIdx.y * 32, tc = blockIdx.x * 32;
        if (tr >= R || tc >= Cc) return;          // block-uniform
        __align__(16) __shared__ u16 t[32][33];
#pragma unroll
        for (int i = 0; i < 4; ++i) {
            const int r = ty + i * 8;
            const long e = zo + (long)(tr + r) * Cc + tc + tx;
            u16 v;
            if (fp32) v = f2b(((const float*)src)[e]);
            else      v = ((const u16*)src)[e];
            t[r][tx] = v;
        }
        __syncthreads();
#pragma unroll
        for (int i = 0; i < 4; ++i) {
            const int r = ty + i * 8;
            dst[(size_t)(tc + r) * R + tr + tx] = t[tx][r];
        }
    } else {
        // ---- convert path ----
        const int c = z - 10;
        const int n = P.cn[c];
        const int lin = blockIdx.y * gridDim.x + blockIdx.x;   // 0..1023
        const int stride = gridDim.x * gridDim.y * 256;        // 262144
        for (int i = lin * 256 + tid; i < n; i += stride) {
            u16 o;
            if (fp32) o = f2b(((const float*)P.cs[c])[i]);
            else      o = ((const u16*)P.cs[c])[i];
            P.cd[c][i] = o;
        }
    }
}

// ---------------------------------------------------------------------------
// XCD-aware block remap (1024-block BN=128 grids)
// ---------------------------------------------------------------------------
__device__ __forceinline__ void tile_swizzle(int& m0, int& n0) {
    const int lin = blockIdx.y * gridDim.x + blockIdx.x;  // 0..1023
    const int xcd = lin & 7;
    const int loc = lin >> 3;
    m0 = (xcd * 16 + (loc & 15)) * 128;
    n0 = (loc >> 4) * 128;
}

// XCD-aware remap for the 512-block BM=256 grid (gemm_hw8_cum)
__device__ __forceinline__ void tile_swizzle8(int& m0, int& n0) {
    const int lin = blockIdx.x;          // 0..511
    const int xcd = lin & 7;
    const int loc = lin >> 3;            // 0..63
    m0 = (xcd * 8 + (loc & 7)) * 256;    // 64 m-tiles
    n0 = (loc >> 3) * 128;               // 8 n-tiles
}

// ---------------------------------------------------------------------------
// 128x128-tile bf16 MFMA GEMM (proven config): BK=64, XOR-swizzled
// global_load_lds staging, bias epilogue, 2 blocks/CU.
// ---------------------------------------------------------------------------
__global__ __launch_bounds__(256, 2) void gemm128(
    const u16* __restrict__ A, const u16* __restrict__ BT,
    const u16* __restrict__ bias, u16* __restrict__ C,
    int M, int N, int K)
{
    __align__(16) __shared__ u16 As[128 * 64];
    __align__(16) __shared__ u16 Bs[128 * 64];

    const int tid  = threadIdx.x;
    const int lane = tid & 63;
    const int wid  = tid >> 6;
    const int wr   = wid >> 1;
    const int wc   = wid & 1;

    int m0, n0;
    tile_swizzle(m0, n0);

    floatx4 acc[4][4] = {};

    const int srow = lane >> 3;
    const int scol = 8 * ((lane & 7) ^ (lane >> 3));
    const int cb   = wid * 4;
    const u16* Ag[4]; const u16* Bg[4];
    u16 *Al[4], *Bl[4];
#pragma unroll
    for (int j = 0; j < 4; ++j) {
        const int c = cb + j;
        const int r = c * 8 + srow;
        Ag[j] = A  + (size_t)(m0 + r) * K + scol;
        Bg[j] = BT + (size_t)(n0 + r) * K + scol;
        Al[j] = As + c * 512;
        Bl[j] = Bs + c * 512;
    }

    const int quad = lane >> 4;
    const int l16  = lane & 15;
    const int swz  = l16 & 7;

    const int nk = K >> 6;
    for (int kt = 0; kt < nk; ++kt) {
        __syncthreads();
#pragma unroll
        for (int j = 0; j < 4; ++j) {
            gld16(Ag[j], Al[j]);  gld16(Bg[j], Bl[j]);
            Ag[j] += 64; Bg[j] += 64;
        }
        __syncthreads();

#pragma unroll
        for (int kk = 0; kk < 2; ++kk) {
            const int slot = ((kk * 4 + quad) ^ swz) * 8;
            bf16x8 af[4], bfr[4];
#pragma unroll
            for (int i = 0; i < 4; ++i) {
                af[i]  = *(const bf16x8*)(As + (wr * 64 + i * 16 + l16) * 64 + slot);
                bfr[i] = *(const bf16x8*)(Bs + (wc * 64 + i * 16 + l16) * 64 + slot);
            }
#pragma unroll
            for (int i = 0; i < 4; ++i)
#pragma unroll
                for (int j = 0; j < 4; ++j)
                    acc[i][j] = __builtin_amdgcn_mfma_f32_16x16x32_bf16(af[i], bfr[j], acc[i][j], 0, 0, 0);
        }
    }

#pragma unroll
    for (int i = 0; i < 4; ++i) {
        const int rowb = m0 + wr * 64 + i * 16 + quad * 4;
#pragma unroll
        for (int j = 0; j < 4; ++j) {
            const int col = n0 + wc * 64 + j * 16 + l16;
            const float bv = b2f(bias[col]);
#pragma unroll
            for (int r = 0; r < 4; ++r)
                C[(size_t)(rowb + r) * N + col] = f2b(acc[i][j][r] + bv);
        }
    }
}

// ---------------------------------------------------------------------------
// MERGED combined-weight precompute + bias fold (grid dim3(8,2,2)):
// z=0: Wp = (tWg @ tWin0) -> [1024,128] = W'^T in BT layout (y selects gate).
// z=1: folded bias b'[j] = dot(bin0, tWg[j,:]) + bg[j]  (256 thr, k-split + LDS).
// ---------------------------------------------------------------------------
__global__ __launch_bounds__(256, 2) void gemm_wp_bias(
    const u16* __restrict__ At, const u16* __restrict__ Ah,
    const u16* __restrict__ BT,
    const u16* __restrict__ binv, const u16* __restrict__ bt0, const u16* __restrict__ bh0,
    u16* __restrict__ Ct, u16* __restrict__ Ch,
    u16* __restrict__ obt, u16* __restrict__ obh)
{
    const int tid = threadIdx.x;
    if (blockIdx.z == 1) {
        __shared__ float part[256];
        const u16* tW = blockIdx.y ? Ah : At;
        const u16* bo = blockIdx.y ? bh0 : bt0;
        u16*       ob = blockIdx.y ? obh : obt;
        const int j  = blockIdx.x * 128 + (tid & 127);
        const int kh = tid >> 7;                       // k-half 0/1
        const u16* row = tW + (size_t)j * HID + kh * 512;
        float acc = 0.f;
        for (int k = 0; k < 512; k += 8) {
            uint4 wv = *(const uint4*)(row + k);
            uint4 bv = *(const uint4*)(binv + kh * 512 + k);
            const u16* w = (const u16*)&wv;
            const u16* b = (const u16*)&bv;
#pragma unroll
            for (int e = 0; e < 8; ++e) acc += b2f(b[e]) * b2f(w[e]);
        }
        part[tid] = acc;
        __syncthreads();
        if (tid < 128)
            ob[j] = f2b(part[tid] + part[tid + 128] + b2f(bo[j]));
        return;
    }

    // z == 0: weight-product GEMM
    const u16* A = blockIdx.y ? Ah : At;
    u16*       C = blockIdx.y ? Ch : Ct;
    const int m0 = blockIdx.x * 128;     // 8 m-tiles
    const int K = HID, N = 128;

    __align__(16) __shared__ u16 As[128 * 64];
    __align__(16) __shared__ u16 Bs[128 * 64];

    const int lane = tid & 63;
    const int wid  = tid >> 6;
    const int wr   = wid >> 1;
    const int wc   = wid & 1;

    floatx4 acc[4][4] = {};

    const int srow = lane >> 3;
    const int scol = 8 * ((lane & 7) ^ (lane >> 3));
    const int cb   = wid * 4;
    const u16* Ag[4]; const u16* Bg[4];
    u16 *Al[4], *Bl[4];
#pragma unroll
    for (int j = 0; j < 4; ++j) {
        const int c = cb + j;
        const int r = c * 8 + srow;
        Ag[j] = A  + (size_t)(m0 + r) * K + scol;
        Bg[j] = BT + (size_t)r * K + scol;          // n0 = 0
        Al[j] = As + c * 512;
        Bl[j] = Bs + c * 512;
    }

    const int quad = lane >> 4;
    const int l16  = lane & 15;
    const int swz  = l16 & 7;

    for (int kt = 0; kt < (K >> 6); ++kt) {
        __syncthreads();
#pragma unroll
        for (int j = 0; j < 4; ++j) {
            gld16(Ag[j], Al[j]);  gld16(Bg[j], Bl[j]);
            Ag[j] += 64; Bg[j] += 64;
        }
        __syncthreads();

#pragma unroll
        for (int kk = 0; kk < 2; ++kk) {
            const int slot = ((kk * 4 + quad) ^ swz) * 8;
            bf16x8 af[4], bfr[4];
#pragma unroll
            for (int i = 0; i < 4; ++i) {
                af[i]  = *(const bf16x8*)(As + (wr * 64 + i * 16 + l16) * 64 + slot);
                bfr[i] = *(const bf16x8*)(Bs + (wc * 64 + i * 16 + l16) * 64 + slot);
            }
#pragma unroll
            for (int i = 0; i < 4; ++i)
#pragma unroll
                for (int j = 0; j < 4; ++j)
                    acc[i][j] = __builtin_amdgcn_mfma_f32_16x16x32_bf16(af[i], bfr[j], acc[i][j], 0, 0, 0);
        }
    }

#pragma unroll
    for (int i = 0; i < 4; ++i) {
        const int rowb = m0 + wr * 64 + i * 16 + quad * 4;
#pragma unroll
        for (int j = 0; j < 4; ++j) {
            const int col = wc * 64 + j * 16 + l16;
#pragma unroll
            for (int r = 0; r < 4; ++r)
                C[(size_t)(rowb + r) * N + col] = f2b(acc[i][j][r]);
        }
    }
}

// ---------------------------------------------------------------------------
// FUSED layer-0 stage-1: triple-gate K=128 highway kernel (proven r7).
//   h = x@Win0+bin; t = sigm(x@W't+b't); hl = tanh(x@W'h+b'h)
//   h_new = h + t*(hl - h)  (h stays fp32 in-register)
// ---------------------------------------------------------------------------
__global__ __launch_bounds__(512, 2) void gemm_hw3(
    const u16* __restrict__ A,      // [M,128] = x
    const u16* __restrict__ WtP,    // [1024,128] = (Win0@Wt00)^T
    const u16* __restrict__ WhP,    // [1024,128] = (Win0@Wh00)^T
    const u16* __restrict__ WiT,    // [1024,128] = Win0^T
    const u16* __restrict__ bpt, const u16* __restrict__ bph,
    const u16* __restrict__ bin,
    u16* __restrict__ Hout,
    int M, int N, int K)            // K = 128
{
    __align__(16) __shared__ u16 As [128 * 64];
    __align__(16) __shared__ u16 Bts[128 * 64];
    __align__(16) __shared__ u16 Bhs[128 * 64];
    __align__(16) __shared__ u16 Bis[128 * 64];

    const int tid  = threadIdx.x;
    const int lane = tid & 63;
    const int wid  = tid >> 6;          // 0..7
    const int wm   = wid >> 2;          // 0..1
    const int wn   = wid & 3;           // 0..3

    int m0, n0;
    tile_swizzle(m0, n0);

    floatx4 acct[4][2] = {};
    floatx4 acch[4][2] = {};
    floatx4 acci[4][2] = {};

    const int srow = lane >> 3;
    const int scol = 8 * ((lane & 7) ^ srow);
    const u16* Ag[2]; const u16* Tg[2]; const u16* Hg[2]; const u16* Ig[2];
    u16 *Al[2], *Tl[2], *Hl[2], *Il[2];
#pragma unroll
    for (int j = 0; j < 2; ++j) {
        const int c = wid * 2 + j;            // 0..15 (8-row chunks)
        const int r = c * 8 + srow;
        Ag[j] = A   + (size_t)(m0 + r) * K + scol;
        Tg[j] = WtP + (size_t)(n0 + r) * K + scol;
        Hg[j] = WhP + (size_t)(n0 + r) * K + scol;
        Ig[j] = WiT + (size_t)(n0 + r) * K + scol;
        Al[j] = As  + c * 512;
        Tl[j] = Bts + c * 512;
        Hl[j] = Bhs + c * 512;
        Il[j] = Bis + c * 512;
    }

    const int quad = lane >> 4;
    const int l16  = lane & 15;
    const int swz  = l16 & 7;

    const int nk = K >> 6;                    // = 2
    for (int kt = 0; kt < nk; ++kt) {
        __syncthreads();
#pragma unroll
        for (int j = 0; j < 2; ++j) {
            gld16(Ag[j], Al[j]);  gld16(Tg[j], Tl[j]);
            gld16(Hg[j], Hl[j]);  gld16(Ig[j], Il[j]);
            Ag[j] += 64; Tg[j] += 64; Hg[j] += 64; Ig[j] += 64;
        }
        __syncthreads();

#pragma unroll
        for (int kk = 0; kk < 2; ++kk) {
            const int slot = ((kk * 4 + quad) ^ swz) * 8;
            bf16x8 af[4], btf[2], bhf[2], bif[2];
#pragma unroll
            for (int i = 0; i < 4; ++i)
                af[i] = *(const bf16x8*)(As + (wm * 64 + i * 16 + l16) * 64 + slot);
#pragma unroll
            for (int j = 0; j < 2; ++j) {
                btf[j] = *(const bf16x8*)(Bts + (wn * 32 + j * 16 + l16) * 64 + slot);
                bhf[j] = *(const bf16x8*)(Bhs + (wn * 32 + j * 16 + l16) * 64 + slot);
                bif[j] = *(const bf16x8*)(Bis + (wn * 32 + j * 16 + l16) * 64 + slot);
            }
#pragma unroll
            for (int i = 0; i < 4; ++i)
#pragma unroll
                for (int j = 0; j < 2; ++j) {
                    acct[i][j] = __builtin_amdgcn_mfma_f32_16x16x32_bf16(af[i], btf[j], acct[i][j], 0, 0, 0);
                    acch[i][j] = __builtin_amdgcn_mfma_f32_16x16x32_bf16(af[i], bhf[j], acch[i][j], 0, 0, 0);
                    acci[i][j] = __builtin_amdgcn_mfma_f32_16x16x32_bf16(af[i], bif[j], acci[i][j], 0, 0, 0);
                }
        }
    }

#pragma unroll
    for (int i = 0; i < 4; ++i) {
        const int rowb = m0 + wm * 64 + i * 16 + quad * 4;
#pragma unroll
        for (int j = 0; j < 2; ++j) {
            const int col = n0 + wn * 32 + j * 16 + l16;
            const float biv = b2f(bin[col]);
            const float btv = b2f(bpt[col]);
            const float bhv = b2f(bph[col]);
#pragma unroll
            for (int r = 0; r < 4; ++r) {
                const float h  = acci[i][j][r] + biv;
                const float tg = sigm(acct[i][j][r] + btv);
                const float hl = tanh_f(acch[i][j][r] + bhv);
                Hout[(size_t)(rowb + r) * N + col] = f2b(h + tg * (hl - h));
            }
        }
    }
}

// ---------------------------------------------------------------------------
// Fused highway GEMM (proven config): BM=128, BN=128 dual-gate, BK=64,
// wave-tile 64x64, 48 KB LDS, 2 blocks/CU.
// ---------------------------------------------------------------------------
__global__ __launch_bounds__(256, 2) void gemm_hw(
    const u16* __restrict__ A,      // [M,K] = h
    const u16* __restrict__ WtT,    // [N,K]
    const u16* __restrict__ WhT,    // [N,K]
    const u16* __restrict__ bt, const u16* __restrict__ bh,
    u16* __restrict__ Hout,
    int M, int N, int K)
{
    __align__(16) __shared__ u16 As [128 * 64];
    __align__(16) __shared__ u16 Bts[128 * 64];
    __align__(16) __shared__ u16 Bhs[128 * 64];

    const int tid  = threadIdx.x;
    const int lane = tid & 63;
    const int wid  = tid >> 6;
    const int wr   = wid >> 1;
    const int wc   = wid & 1;

    int m0, n0;
    tile_swizzle(m0, n0);

    floatx4 acct[4][4] = {};
    floatx4 acch[4][4] = {};

    const int srow = lane >> 3;
    const int scol = 8 * ((lane & 7) ^ (lane >> 3));
    const int cb   = wid * 4;
    const u16* Ag[4]; const u16* Tg[4]; const u16* Hg[4];
    u16 *Al[4], *Tl[4], *Hl[4];
#pragma unroll
    for (int j = 0; j < 4; ++j) {
        const int c = cb + j;
        const int r = c * 8 + srow;
        Ag[j] = A   + (size_t)(m0 + r) * K + scol;
        Tg[j] = WtT + (size_t)(n0 + r) * K + scol;
        Hg[j] = WhT + (size_t)(n0 + r) * K + scol;
        Al[j] = As  + c * 512;
        Tl[j] = Bts + c * 512;
        Hl[j] = Bhs + c * 512;
    }

    const int quad = lane >> 4;
    const int l16  = lane & 15;
    const int swz  = l16 & 7;

    const int nk = K >> 6;
    for (int kt = 0; kt < nk; ++kt) {
        __syncthreads();
#pragma unroll
        for (int j = 0; j < 4; ++j) {
            gld16(Ag[j], Al[j]);  gld16(Tg[j], Tl[j]);  gld16(Hg[j], Hl[j]);
            Ag[j] += 64; Tg[j] += 64; Hg[j] += 64;
        }
        __syncthreads();

#pragma unroll
        for (int kk = 0; kk < 2; ++kk) {
            const int slot = ((kk * 4 + quad) ^ swz) * 8;
            bf16x8 af[4], btf[4], bhf[4];
#pragma unroll
            for (int i = 0; i < 4; ++i) {
                af[i]  = *(const bf16x8*)(As  + (wr * 64 + i * 16 + l16) * 64 + slot);
                btf[i] = *(const bf16x8*)(Bts + (wc * 64 + i * 16 + l16) * 64 + slot);
                bhf[i] = *(const bf16x8*)(Bhs + (wc * 64 + i * 16 + l16) * 64 + slot);
            }
#pragma unroll
            for (int i = 0; i < 4; ++i)
#pragma unroll
                for (int j = 0; j < 4; ++j) {
                    acct[i][j] = __builtin_amdgcn_mfma_f32_16x16x32_bf16(af[i], btf[j], acct[i][j], 0, 0, 0);
                    acch[i][j] = __builtin_amdgcn_mfma_f32_16x16x32_bf16(af[i], bhf[j], acch[i][j], 0, 0, 0);
                }
        }
    }

#pragma unroll
    for (int i = 0; i < 4; ++i) {
        const int rowb = m0 + wr * 64 + i * 16 + quad * 4;
#pragma unroll
        for (int j = 0; j < 4; ++j) {
            const int col = n0 + wc * 64 + j * 16 + l16;
            const float btv = b2f(bt[col]);
            const float bhv = b2f(bh[col]);
#pragma unroll
            for (int r = 0; r < 4; ++r) {
                const size_t idx = (size_t)(rowb + r) * N + col;
                const float hold = b2f(A[idx]);
                const float tg = sigm(acct[i][j][r] + btv);
                const float hl = tanh_f(acch[i][j][r] + bhv);
                Hout[idx] = f2b(hold + tg * (hl - hold));
            }
        }
    }
}

// ---------------------------------------------------------------------------
// Final-stage highway GEMM (proven config): identical K-loop; epilogue
// reduces h_new over the tile's 128 rows and writes NON-ATOMIC partials into
// hpart[slot][b][col], slot = mtile_parity*2 + wr.
// ---------------------------------------------------------------------------
__global__ __launch_bounds__(256, 2) void gemm_hw_sum(
    const u16* __restrict__ A,      // [M,K] = h
    const u16* __restrict__ WtT,    // [N,K]
    const u16* __restrict__ WhT,    // [N,K]
    const u16* __restrict__ bt, const u16* __restrict__ bh,
    float* __restrict__ hpart,      // [4, BATCH, HID] fp32 partials
    int M, int N, int K)
{
    __align__(16) __shared__ u16 As [128 * 64];
    __align__(16) __shared__ u16 Bts[128 * 64];
    __align__(16) __shared__ u16 Bhs[128 * 64];

    const int tid  = threadIdx.x;
    const int lane = tid & 63;
    const int wid  = tid >> 6;
    const int wr   = wid >> 1;
    const int wc   = wid & 1;

    int m0, n0;
    tile_swizzle(m0, n0);

    floatx4 acct[4][4] = {};
    floatx4 acch[4][4] = {};

    const int srow = lane >> 3;
    const int scol = 8 * ((lane & 7) ^ (lane >> 3));
    const int cb   = wid * 4;
    const u16* Ag[4]; const u16* Tg[4]; const u16* Hg[4];
    u16 *Al[4], *Tl[4], *Hl[4];
#pragma unroll
    for (int j = 0; j < 4; ++j) {
        const int c = cb + j;
        const int r = c * 8 + srow;
        Ag[j] = A   + (size_t)(m0 + r) * K + scol;
        Tg[j] = WtT + (size_t)(n0 + r) * K + scol;
        Hg[j] = WhT + (size_t)(n0 + r) * K + scol;
        Al[j] = As  + c * 512;
        Tl[j] = Bts + c * 512;
        Hl[j] = Bhs + c * 512;
    }

    const int quad = lane >> 4;
    const int l16  = lane & 15;
    const int swz  = l16 & 7;

    const int nk = K >> 6;
    for (int kt = 0; kt < nk; ++kt) {
        __syncthreads();
#pragma unroll
        for (int j = 0; j < 4; ++j) {
            gld16(Ag[j], Al[j]);  gld16(Tg[j], Tl[j]);  gld16(Hg[j], Hl[j]);
            Ag[j] += 64; Tg[j] += 64; Hg[j] += 64;
        }
        __syncthreads();

#pragma unroll
        for (int kk = 0; kk < 2; ++kk) {
            const int slot = ((kk * 4 + quad) ^ swz) * 8;
            bf16x8 af[4], btf[4], bhf[4];
#pragma unroll
            for (int i = 0; i < 4; ++i) {
                af[i]  = *(const bf16x8*)(As  + (wr * 64 + i * 16 + l16) * 64 + slot);
                btf[i] = *(const bf16x8*)(Bts + (wc * 64 + i * 16 + l16) * 64 + slot);
                bhf[i] = *(const bf16x8*)(Bhs + (wc * 64 + i * 16 + l16) * 64 + slot);
            }
#pragma unroll
            for (int i = 0; i < 4; ++i)
#pragma unroll
                for (int j = 0; j < 4; ++j) {
                    acct[i][j] = __builtin_amdgcn_mfma_f32_16x16x32_bf16(af[i], btf[j], acct[i][j], 0, 0, 0);
                    acch[i][j] = __builtin_amdgcn_mfma_f32_16x16x32_bf16(af[i], bhf[j], acch[i][j], 0, 0, 0);
                }
        }
    }

    const int b    = m0 >> 8;
    const int slot = ((m0 >> 7) & 1) * 2 + wr;
#pragma unroll
    for (int j = 0; j < 4; ++j) {
        const int col = n0 + wc * 64 + j * 16 + l16;
        const float btv = b2f(bt[col]);
        const float bhv = b2f(bh[col]);
        float colsum = 0.f;
#pragma unroll
        for (int i = 0; i < 4; ++i) {
            const int rowb = m0 + wr * 64 + i * 16 + quad * 4;
#pragma unroll
            for (int r = 0; r < 4; ++r) {
                const size_t idx = (size_t)(rowb + r) * N + col;
                const float hold = b2f(A[idx]);
                const float tg = sigm(acct[i][j][r] + btv);
                const float hl = tanh_f(acch[i][j][r] + bhv);
                colsum += hold + tg * (hl - hold);
            }
        }
        colsum += __shfl_xor(colsum, 16, 64);
        colsum += __shfl_xor(colsum, 32, 64);
        if (quad == 0)
            hpart[((size_t)(slot * BATCH + b)) * HID + col] = colsum;
    }
}

// ---------------------------------------------------------------------------
// 8-wave pipelined dual-gate highway K-loop (counted-vmcnt schedule — the
// PROVEN 92.5 µs cum mainloop): BM=256, BN=128, BK=64, 512 thr,
// LDS = 2 x (A 32K | Bt 16K | Bh 16K) = 128 KiB double-buffered.
// ---------------------------------------------------------------------------
__device__ __forceinline__ void hw8_mainloop(
    u16* lds,
    const u16* __restrict__ A, const u16* __restrict__ WtT, const u16* __restrict__ WhT,
    int m0, int n0, int K,
    floatx4 (&acct)[4][4], floatx4 (&acch)[4][4])
{
    const int tid  = threadIdx.x;
    const int lane = tid & 63;
    const int wid  = tid >> 6;          // 0..7
    const int wr   = wid >> 1;          // 0..3
    const int wc   = wid & 1;

    const int srow = lane >> 3;
    const int scol = 8 * ((lane & 7) ^ srow);

    const u16* Ag = A   + (size_t)(m0 + wid * 32 + srow) * K + scol;
    const u16* Tg = WtT + (size_t)(n0 + wid * 16 + srow) * K + scol;
    const u16* Hg = WhT + (size_t)(n0 + wid * 16 + srow) * K + scol;
    const size_t K8 = (size_t)K * 8;

    u16* dA = lds + wid * 2048;
    u16* dT = lds + 16384 + wid * 1024;
    u16* dH = lds + 24576 + wid * 1024;

    const int quad = lane >> 4;
    const int l16  = lane & 15;
    const int swz  = l16 & 7;
    const int s0 = (quad ^ swz) * 8;
    const int s1 = ((4 + quad) ^ swz) * 8;
    const int ra = wr * 64 + l16;
    const int rb = wc * 64 + l16;

    gld16(Tg,           dT);
    gld16(Tg +     K8,  dT + 512);
    gld16(Ag,           dA);
    gld16(Ag +     K8,  dA + 512);
    gld16(Ag + 2 * K8,  dA + 1024);
    gld16(Ag + 3 * K8,  dA + 1536);
    gld16(Hg,           dH);
    gld16(Hg +     K8,  dH + 512);
    Ag += 64; Tg += 64; Hg += 64;
    vm_bar<2>();                               // T+A of tile 0 ready; H in flight

    const int nk = K >> 6;
    for (int kt = 0; kt < nk; ++kt) {
        const int  cur = kt & 1;
        const int  nb  = (cur ^ 1) * 32768;
        const bool pf  = (kt + 1 < nk);
        const u16* Sa = lds + cur * 32768;
        const u16* St = Sa + 16384;
        const u16* Sh = Sa + 24576;

        bf16x8 af0[4], af1[4], bq[4];

        // ---- P0: T-gate kk0 ----
#pragma unroll
        for (int i = 0; i < 4; ++i) {
            af0[i] = *(const bf16x8*)(Sa + (ra + i * 16) * 64 + s0);
            bq[i]  = *(const bf16x8*)(St + (rb + i * 16) * 64 + s0);
        }
        if (pf) {
            gld16(Tg,      dT + nb);  gld16(Tg + K8, dT + nb + 512);
            gld16(Ag,      dA + nb);  gld16(Ag + K8, dA + nb + 512);
        }
        bar_sync();
        __builtin_amdgcn_s_setprio(1);
#pragma unroll
        for (int i = 0; i < 4; ++i)
#pragma unroll
            for (int j = 0; j < 4; ++j)
                acct[i][j] = __builtin_amdgcn_mfma_f32_16x16x32_bf16(af0[i], bq[j], acct[i][j], 0, 0, 0);
        __builtin_amdgcn_s_setprio(0);

        // ---- P1: T-gate kk1 ----
#pragma unroll
        for (int i = 0; i < 4; ++i) {
            af1[i] = *(const bf16x8*)(Sa + (ra + i * 16) * 64 + s1);
            bq[i]  = *(const bf16x8*)(St + (rb + i * 16) * 64 + s1);
        }
        if (pf) {
            gld16(Ag + 2 * K8, dA + nb + 1024);
            gld16(Ag + 3 * K8, dA + nb + 1536);
            vm_bar<6>();                       // forces H(kt); 6 newer stay in flight
        } else {
            vm_bar<0>();                       // last tile: full drain
        }
        __builtin_amdgcn_s_setprio(1);
#pragma unroll
        for (int i = 0; i < 4; ++i)
#pragma unroll
            for (int j = 0; j < 4; ++j)
                acct[i][j] = __builtin_amdgcn_mfma_f32_16x16x32_bf16(af1[i], bq[j], acct[i][j], 0, 0, 0);
        __builtin_amdgcn_s_setprio(0);

        // ---- P2: H-gate kk0 ----
#pragma unroll
        for (int i = 0; i < 4; ++i)
            bq[i] = *(const bf16x8*)(Sh + (rb + i * 16) * 64 + s0);
        bar_sync();
        __builtin_amdgcn_s_setprio(1);
#pragma unroll
        for (int i = 0; i < 4; ++i)
#pragma unroll
            for (int j = 0; j < 4; ++j)
                acch[i][j] = __builtin_amdgcn_mfma_f32_16x16x32_bf16(af0[i], bq[j], acch[i][j], 0, 0, 0);
        __builtin_amdgcn_s_setprio(0);

        // ---- P3: H-gate kk1 ----
#pragma unroll
        for (int i = 0; i < 4; ++i)
            bq[i] = *(const bf16x8*)(Sh + (rb + i * 16) * 64 + s1);
        if (pf) {
            gld16(Hg,      dH + nb);
            gld16(Hg + K8, dH + nb + 512);
            vm_bar<2>();                       // forces T+A(kt+1); H(kt+1) in flight
        } else {
            bar_sync();
        }
        __builtin_amdgcn_s_setprio(1);
#pragma unroll
        for (int i = 0; i < 4; ++i)
#pragma unroll
            for (int j = 0; j < 4; ++j)
                acch[i][j] = __builtin_amdgcn_mfma_f32_16x16x32_bf16(af1[i], bq[j], acch[i][j], 0, 0, 0);
        __builtin_amdgcn_s_setprio(0);

        Ag += 64; Tg += 64; Hg += 64;
    }
}

// ---------------------------------------------------------------------------
// Layer-0 stage-2 highway GEMM with FUSED cumsum-over-t (proven: 92.5 µs).
// BM=256 == SEQ: each block owns one full batch's 256 timesteps x 128 cols.
// ---------------------------------------------------------------------------
__global__ __launch_bounds__(512, 2) void gemm_hw8_cum(
    const u16* __restrict__ A,      // [M,K] = h
    const u16* __restrict__ WtT,    // [N,K]
    const u16* __restrict__ WhT,    // [N,K]
    const u16* __restrict__ bt, const u16* __restrict__ bh,
    u16* __restrict__ Y,            // [M,N] y0 = cumsum_t(h_new)
    int M, int N, int K)
{
    __align__(16) __shared__ u16 lds[65536];   // 128 KiB (mainloop), reused below
    __shared__ float tot[512];

    int m0, n0;
    tile_swizzle8(m0, n0);

    floatx4 acct[4][4] = {};
    floatx4 acch[4][4] = {};
    hw8_mainloop(lds, A, WtT, WhT, m0, n0, K, acct, acch);

    const int tid  = threadIdx.x;
    const int lane = tid & 63;
    const int wid  = tid >> 6;
    const int wr   = wid >> 1;
    const int wc   = wid & 1;
    const int quad = lane >> 4;
    const int l16  = lane & 15;

    __syncthreads();   // drain per-wave LDS ops before buffer reuse

    // stage h_new (bf16) into lds[row][col] with padded stride CUMP
#pragma unroll
    for (int i = 0; i < 4; ++i) {
        const int rowl = wr * 64 + i * 16 + quad * 4;
#pragma unroll
        for (int j = 0; j < 4; ++j) {
            const int coll = wc * 64 + j * 16 + l16;
            const float btv = b2f(bt[n0 + coll]);
            const float bhv = b2f(bh[n0 + coll]);
#pragma unroll
            for (int r = 0; r < 4; ++r) {
                const size_t idx = (size_t)(m0 + rowl + r) * N + n0 + coll;
                const float hold = b2f(A[idx]);
                const float tg = sigm(acct[i][j][r] + btv);
                const float hl = tanh_f(acch[i][j][r] + bhv);
                lds[(rowl + r) * CUMP + coll] = f2b(hold + tg * (hl - hold));
            }
        }
    }
    __syncthreads();

    // segmented scan: seg = tid>>7 (64 t's each), col = tid&127
    const int seg  = tid >> 7;
    const int colc = tid & 127;
    const int base = seg * 64 * CUMP + colc;
    {
        float local = 0.f;
#pragma unroll 8
        for (int t = 0; t < 64; ++t)
            local += b2f(lds[base + t * CUMP]);
        tot[seg * 128 + colc] = local;
    }
    __syncthreads();
    {
        float off = 0.f;
#pragma unroll
        for (int s = 0; s < 3; ++s)
            off += (s < seg) ? tot[s * 128 + colc] : 0.f;
        float acc = off;
#pragma unroll 8
        for (int t = 0; t < 64; ++t) {
            const int o = base + t * CUMP;
            acc += b2f(lds[o]);
            lds[o] = f2b(acc);
        }
    }
    __syncthreads();

    // coalesced tile write: 16 iters x 512 thr x 4 u16 = 256x128
#pragma unroll
    for (int it = 0; it < 16; ++it) {
        const int o   = it * 2048 + tid * 4;
        const int row = o >> 7;
        const int col = o & 127;
        *(uint2*)&Y[(size_t)(m0 + row) * N + n0 + col] =
            *(const uint2*)&lds[row * CUMP + col];
    }
}

// final fc (r11: 256 thr, 2-way k-split): sums the 4 hpart slots into LDS,
// then each (o, kh) thread dots its 512-element half; halves combined in LDS.
// fp32 accumulation order within each half matches the old kernel's halves.
__global__ void fc_final(const float* __restrict__ hp, const void* __restrict__ W,
                         const void* __restrict__ bias, void* __restrict__ out) {
    __shared__ float sh[HID];
    __shared__ float part[256];
    const int fp32 = is_fp32((const u16*)W, threadIdx.x);
    const int b = blockIdx.x, tid = threadIdx.x;    // 64 blocks x 256 threads
    for (int k = tid; k < HID; k += 256) {
        float v = 0.f;
#pragma unroll
        for (int s = 0; s < 4; ++s)
            v += hp[((size_t)(s * BATCH + b)) * HID + k];
        sh[k] = v;
    }
    __syncthreads();
    const int o  = tid & 127;
    const int kh = tid >> 7;            // k-half 0/1
    float acc = 0.f;
    if (fp32) {
        for (int k = kh * 512; k < kh * 512 + 512; ++k)
            acc += sh[k] * ((const float*)W)[(size_t)k * OUTDIM + o];
        part[tid] = acc;
        __syncthreads();
        if (tid < 128)
            ((float*)out)[b * OUTDIM + tid] =
                part[tid] + part[tid + 128] + ((const float*)bias)[tid];
    } else {
        for (int k = kh * 512; k < kh * 512 + 512; ++k)
            acc += sh[k] * b2f(((const u16*)W)[(size_t)k * OUTDIM + o]);
        part[tid] = acc;
        __syncthreads();
        if (tid < 128)
            ((u16*)out)[b * OUTDIM + tid] =
                f2b(part[tid] + part[tid + 128] + b2f(((const u16*)bias)[tid]));
    }
}

// ---------------------------------------------------------------------------
extern "C" void kernel_launch(void* const* d_in, const int* in_sizes, int n_in,
                              void* d_out, int out_size, void* d_ws, size_t ws_size,
                              hipStream_t stream) {
    const void* x      = d_in[0];
    const void* l0_Win = d_in[1];
    const void* l0_bin = d_in[2];
    const void* l0_Wh  = d_in[3];
    const void* l0_bh  = d_in[4];
    const void* l0_Wt  = d_in[5];
    const void* l0_bt  = d_in[6];
    const void* l1_Win = d_in[7];
    const void* l1_bin = d_in[8];
    const void* l1_Wh  = d_in[9];
    const void* l1_bh  = d_in[10];
    const void* l1_Wt  = d_in[11];
    const void* l1_bt  = d_in[12];
    const void* fc_W   = d_in[13];
    const void* fc_b   = d_in[14];

    char* ws = (char*)d_ws;
    u16* Pa = (u16*)(ws);                       // 32 MB
    u16* Pb = (u16*)(ws + 33554432);            // 32 MB; xc at its base
    u16* xc = Pb;                               // [16384,128] clean bf16 x
    u16* tW = (u16*)(ws + 67108864);
    u16* tWin0 = tW;                  // [1024,128]
    u16* tWt00 = tWin0 + 131072;      // each [1024,1024]
    u16* tWt01 = tWt00 + 1048576;
    u16* tWh00 = tWt01 + 1048576;
    u16* tWh01 = tWh00 + 1048576;
    u16* tWin1 = tWh01 + 1048576;
    u16* tWt10 = tWin1 + 1048576;
    u16* tWt11 = tWt10 + 1048576;
    u16* tWh10 = tWt11 + 1048576;
    u16* tWh11 = tWh10 + 1048576;
    u16* smallb = tWh11 + 1048576;    // bias copies
    u16* binc0 = smallb;              // 1024
    u16* bhc0  = binc0 + 1024;        // 2048
    u16* btc0  = bhc0 + 2048;         // 2048
    u16* binc1 = btc0 + 2048;         // 1024
    u16* bhc1  = binc1 + 1024;        // 2048
    u16* btc1  = bhc1 + 2048;         // 2048
    u16* Win0c = btc1 + 2048;         // [128,1024] clean orig-orientation Win0
    u16* Wpt   = Win0c + 131072;      // [1024,128] = (Win0@Wt00)^T
    u16* Wph   = Wpt + 131072;        // [1024,128] = (Win0@Wh00)^T
    u16* bpt   = Wph + 131072;        // [1024] folded t-bias
    u16* bph   = bpt + 1024;          // [1024] folded h-bias
    float* hpart = (float*)Pa;        // [4,64,1024] fp32 partials; Pa dead at tail

    const u16* probe = (const u16*)l0_Wh;   // dtype probe tensor

    const long DD = (long)HID * HID;
    PrepList P;
    P.ts[0] = l0_Win; P.td[0] = tWin0; P.tR[0] = INDIM; P.tC[0] = HID; P.toff[0] = 0;
    P.ts[1] = l0_Wt;  P.td[1] = tWt00; P.tR[1] = HID;   P.tC[1] = HID; P.toff[1] = 0;
    P.ts[2] = l0_Wt;  P.td[2] = tWt01; P.tR[2] = HID;   P.tC[2] = HID; P.toff[2] = DD;
    P.ts[3] = l0_Wh;  P.td[3] = tWh00; P.tR[3] = HID;   P.tC[3] = HID; P.toff[3] = 0;
    P.ts[4] = l0_Wh;  P.td[4] = tWh01; P.tR[4] = HID;   P.tC[4] = HID; P.toff[4] = DD;
    P.ts[5] = l1_Win; P.td[5] = tWin1; P.tR[5] = HID;   P.tC[5] = HID; P.toff[5] = 0;
    P.ts[6] = l1_Wt;  P.td[6] = tWt10; P.tR[6] = HID;   P.tC[6] = HID; P.toff[6] = 0;
    P.ts[7] = l1_Wt;  P.td[7] = tWt11; P.tR[7] = HID;   P.tC[7] = HID; P.toff[7] = DD;
    P.ts[8] = l1_Wh;  P.td[8] = tWh10; P.tR[8] = HID;   P.tC[8] = HID; P.toff[8] = 0;
    P.ts[9] = l1_Wh;  P.td[9] = tWh11; P.tR[9] = HID;   P.tC[9] = HID; P.toff[9] = DD;
    P.cs[0] = x;      P.cd[0] = xc;    P.cn[0] = MROWS * INDIM;
    P.cs[1] = l0_bin; P.cd[1] = binc0; P.cn[1] = HID;
    P.cs[2] = l0_bh;  P.cd[2] = bhc0;  P.cn[2] = 2 * HID;
    P.cs[3] = l0_bt;  P.cd[3] = btc0;  P.cn[3] = 2 * HID;
    P.cs[4] = l1_bin; P.cd[4] = binc1; P.cn[4] = HID;
    P.cs[5] = l1_bh;  P.cd[5] = bhc1;  P.cn[5] = 2 * HID;
    P.cs[6] = l1_bt;  P.cd[6] = btc1;  P.cn[6] = 2 * HID;
    P.cs[7] = l0_Win; P.cd[7] = Win0c; P.cn[7] = INDIM * HID;
    prep18<<<dim3(32, 32, 18), 256, 0, stream>>>(P, probe);

    // ---- layer-0 weight folding + bias fold (one launch) ----
    gemm_wp_bias<<<dim3(8, 2, 2), 256, 0, stream>>>(tWt00, tWh00, Win0c,
                                                    binc0, btc0, bhc0,
                                                    Wpt, Wph, bpt, bph);

    // ---- layer 0 ----
    // stage 1: fused triple-gate K=128 (replaces gemm128 + gemm_hw)
    gemm_hw3<<<dim3(8, 128), 512, 0, stream>>>(xc, Wpt, Wph, tWin0, bpt, bph, binc0,
                                               Pa, MROWS, HID, INDIM);
    // stage 2 with fused cumsum-over-t -> Pb = y0
    gemm_hw8_cum<<<512, 512, 0, stream>>>(Pa, tWt01, tWh01, btc0 + HID, bhc0 + HID, Pb, MROWS, HID, HID);

    // ---- layer 1 ----
    gemm128<<<dim3(8, 128), 256, 0, stream>>>(Pb, tWin1, binc1, Pa, MROWS, HID, HID);
    gemm_hw<<<dim3(8, 128), 256, 0, stream>>>(Pa, tWt10, tWh10, btc1, bhc1, Pb, MROWS, HID, HID);
    // final depth stage: non-atomic partial sums into hpart (Pa dead)
    gemm_hw_sum<<<dim3(8, 128), 256, 0, stream>>>(Pb, tWt11, tWh11, btc1 + HID, bhc1 + HID,
                                                  hpart, MROWS, HID, HID);

    // ---- tail ----
    fc_final<<<64, 256, 0, stream>>>(hpart, fc_W, fc_b, d_out);
}

// Round 12
// 447.393 us; speedup vs baseline: 1.2699x; 1.2699x over previous
//
#include <hip/hip_runtime.h>

typedef unsigned short u16;
typedef unsigned int u32;
typedef __bf16 bf16x8 __attribute__((ext_vector_type(8)));
typedef float floatx4 __attribute__((ext_vector_type(4)));

#define HID 1024
#define BATCH 64
#define SEQ 256
#define INDIM 128
#define OUTDIM 128
#define MROWS (BATCH*SEQ)   // 16384
#define CUMP 140            // padded LDS row stride (u16) for the cumsum epilogue

__device__ __forceinline__ float b2f(u16 u) {
    union { u32 u; float f; } v; v.u = ((u32)u) << 16; return v.f;
}
__device__ __forceinline__ u16 f2b(float f) {
    union { float f; u32 u; } v; v.f = f;
    u32 x = v.u;
    x += 0x7fffu + ((x >> 16) & 1u);
    return (u16)(x >> 16);
}
__device__ __forceinline__ float sigm(float x) { return 1.f / (1.f + __expf(-x)); }
__device__ __forceinline__ float tanh_f(float x) { return 2.f / (1.f + __expf(-2.f * x)) - 1.f; }

__device__ __forceinline__ void gld16(const u16* g, u16* l) {
    __builtin_amdgcn_global_load_lds(
        (const __attribute__((address_space(1))) void*)g,
        (__attribute__((address_space(3))) void*)l, 16, 0, 0);
}

// raw barrier (no vmcnt drain) + compiler memory fences
__device__ __forceinline__ void bar_sync() {
    asm volatile("" ::: "memory");
    __builtin_amdgcn_s_barrier();
    asm volatile("" ::: "memory");
}
// counted vmcnt wait + barrier: loads stay in flight across the barrier
template <int N>
__device__ __forceinline__ void vm_bar() {
    asm volatile("s_waitcnt vmcnt(%0)" :: "n"(N) : "memory");
    __builtin_amdgcn_s_barrier();
    asm volatile("" ::: "memory");
}

// ---------------------------------------------------------------------------
// inline wave-ballot dtype self-detect (probe = l0_Wh / fc_W, uniform ±1/32)
// ---------------------------------------------------------------------------
__device__ __forceinline__ int is_fp32(const u16* probe, int tid) {
    const int lane = tid & 63;
    const int e = (probe[lane * 7] >> 7) & 0xff;
    return __ballot(e >= 127) != 0ULL;
}

// ---------------------------------------------------------------------------
// MERGED prep kernel: z = 0..9 transpose 10 weight matrices [R,C]->[C,R];
// z = 10..17 convert 8 tensors (x + 6 bias vectors + Win0) to clean bf16.
// ---------------------------------------------------------------------------
struct PrepList {
    const void* ts[10]; u16* td[10]; int tR[10]; int tC[10]; long toff[10];
    const void* cs[8];  u16* cd[8];  int cn[8];
};

__global__ void prep18(PrepList P, const u16* __restrict__ probe) {
    const int tid  = threadIdx.x;                 // 256
    const int fp32 = is_fp32(probe, tid);         // before any divergence
    const int z = blockIdx.z;
    if (z < 10) {
        // ---- transpose path ----
        const int tx = tid & 31, ty = tid >> 5;   // (32,8)
        const void* src = P.ts[z];
        u16*        dst = P.td[z];
        const int R  = P.tR[z];
        const int Cc = P.tC[z];
        const long zo = P.toff[z];
        const int tr = blockIdx.y * 32, tc = blockIdx.x * 32;
        if (tr >= R || tc >= Cc) return;          // block-uniform
        __align__(16) __shared__ u16 t[32][33];
#pragma unroll
        for (int i = 0; i < 4; ++i) {
            const int r = ty + i * 8;
            const long e = zo + (long)(tr + r) * Cc + tc + tx;
            u16 v;
            if (fp32) v = f2b(((const float*)src)[e]);
            else      v = ((const u16*)src)[e];
            t[r][tx] = v;
        }
        __syncthreads();
#pragma unroll
        for (int i = 0; i < 4; ++i) {
            const int r = ty + i * 8;
            dst[(size_t)(tc + r) * R + tr + tx] = t[tx][r];
        }
    } else {
        // ---- convert path ----
        const int c = z - 10;
        const int n = P.cn[c];
        const int lin = blockIdx.y * gridDim.x + blockIdx.x;   // 0..1023
        const int stride = gridDim.x * gridDim.y * 256;        // 262144
        for (int i = lin * 256 + tid; i < n; i += stride) {
            u16 o;
            if (fp32) o = f2b(((const float*)P.cs[c])[i]);
            else      o = ((const u16*)P.cs[c])[i];
            P.cd[c][i] = o;
        }
    }
}

// ---------------------------------------------------------------------------
// XCD-aware block remap (1024-block BN=128 grids)
// ---------------------------------------------------------------------------
__device__ __forceinline__ void tile_swizzle(int& m0, int& n0) {
    const int lin = blockIdx.y * gridDim.x + blockIdx.x;  // 0..1023
    const int xcd = lin & 7;
    const int loc = lin >> 3;
    m0 = (xcd * 16 + (loc & 15)) * 128;
    n0 = (loc >> 4) * 128;
}

// XCD-aware remap for the 512-block BM=256 grid (gemm_hw8_cum)
__device__ __forceinline__ void tile_swizzle8(int& m0, int& n0) {
    const int lin = blockIdx.x;          // 0..511
    const int xcd = lin & 7;
    const int loc = lin >> 3;            // 0..63
    m0 = (xcd * 8 + (loc & 7)) * 256;    // 64 m-tiles
    n0 = (loc >> 3) * 128;               // 8 n-tiles
}

// ---------------------------------------------------------------------------
// 128x128-tile bf16 MFMA GEMM (proven config): BK=64, XOR-swizzled
// global_load_lds staging, bias epilogue, 2 blocks/CU.
// ---------------------------------------------------------------------------
__global__ __launch_bounds__(256, 2) void gemm128(
    const u16* __restrict__ A, const u16* __restrict__ BT,
    const u16* __restrict__ bias, u16* __restrict__ C,
    int M, int N, int K)
{
    __align__(16) __shared__ u16 As[128 * 64];
    __align__(16) __shared__ u16 Bs[128 * 64];

    const int tid  = threadIdx.x;
    const int lane = tid & 63;
    const int wid  = tid >> 6;
    const int wr   = wid >> 1;
    const int wc   = wid & 1;

    int m0, n0;
    tile_swizzle(m0, n0);

    floatx4 acc[4][4] = {};

    const int srow = lane >> 3;
    const int scol = 8 * ((lane & 7) ^ (lane >> 3));
    const int cb   = wid * 4;
    const u16* Ag[4]; const u16* Bg[4];
    u16 *Al[4], *Bl[4];
#pragma unroll
    for (int j = 0; j < 4; ++j) {
        const int c = cb + j;
        const int r = c * 8 + srow;
        Ag[j] = A  + (size_t)(m0 + r) * K + scol;
        Bg[j] = BT + (size_t)(n0 + r) * K + scol;
        Al[j] = As + c * 512;
        Bl[j] = Bs + c * 512;
    }

    const int quad = lane >> 4;
    const int l16  = lane & 15;
    const int swz  = l16 & 7;

    const int nk = K >> 6;
    for (int kt = 0; kt < nk; ++kt) {
        __syncthreads();
#pragma unroll
        for (int j = 0; j < 4; ++j) {
            gld16(Ag[j], Al[j]);  gld16(Bg[j], Bl[j]);
            Ag[j] += 64; Bg[j] += 64;
        }
        __syncthreads();

#pragma unroll
        for (int kk = 0; kk < 2; ++kk) {
            const int slot = ((kk * 4 + quad) ^ swz) * 8;
            bf16x8 af[4], bfr[4];
#pragma unroll
            for (int i = 0; i < 4; ++i) {
                af[i]  = *(const bf16x8*)(As + (wr * 64 + i * 16 + l16) * 64 + slot);
                bfr[i] = *(const bf16x8*)(Bs + (wc * 64 + i * 16 + l16) * 64 + slot);
            }
#pragma unroll
            for (int i = 0; i < 4; ++i)
#pragma unroll
                for (int j = 0; j < 4; ++j)
                    acc[i][j] = __builtin_amdgcn_mfma_f32_16x16x32_bf16(af[i], bfr[j], acc[i][j], 0, 0, 0);
        }
    }

#pragma unroll
    for (int i = 0; i < 4; ++i) {
        const int rowb = m0 + wr * 64 + i * 16 + quad * 4;
#pragma unroll
        for (int j = 0; j < 4; ++j) {
            const int col = n0 + wc * 64 + j * 16 + l16;
            const float bv = b2f(bias[col]);
#pragma unroll
            for (int r = 0; r < 4; ++r)
                C[(size_t)(rowb + r) * N + col] = f2b(acc[i][j][r] + bv);
        }
    }
}

// ---------------------------------------------------------------------------
// MERGED combined-weight precompute + bias fold (grid dim3(8,2,2)):
// z=0: Wp = (tWg @ tWin0) -> [1024,128] = W'^T in BT layout (y selects gate).
// z=1: folded bias b'[j] = dot(bin0, tWg[j,:]) + bg[j]  (256 thr, k-split + LDS).
// ---------------------------------------------------------------------------
__global__ __launch_bounds__(256, 2) void gemm_wp_bias(
    const u16* __restrict__ At, const u16* __restrict__ Ah,
    const u16* __restrict__ BT,
    const u16* __restrict__ binv, const u16* __restrict__ bt0, const u16* __restrict__ bh0,
    u16* __restrict__ Ct, u16* __restrict__ Ch,
    u16* __restrict__ obt, u16* __restrict__ obh)
{
    const int tid = threadIdx.x;
    if (blockIdx.z == 1) {
        __shared__ float part[256];
        const u16* tW = blockIdx.y ? Ah : At;
        const u16* bo = blockIdx.y ? bh0 : bt0;
        u16*       ob = blockIdx.y ? obh : obt;
        const int j  = blockIdx.x * 128 + (tid & 127);
        const int kh = tid >> 7;                       // k-half 0/1
        const u16* row = tW + (size_t)j * HID + kh * 512;
        float acc = 0.f;
        for (int k = 0; k < 512; k += 8) {
            uint4 wv = *(const uint4*)(row + k);
            uint4 bv = *(const uint4*)(binv + kh * 512 + k);
            const u16* w = (const u16*)&wv;
            const u16* b = (const u16*)&bv;
#pragma unroll
            for (int e = 0; e < 8; ++e) acc += b2f(b[e]) * b2f(w[e]);
        }
        part[tid] = acc;
        __syncthreads();
        if (tid < 128)
            ob[j] = f2b(part[tid] + part[tid + 128] + b2f(bo[j]));
        return;
    }

    // z == 0: weight-product GEMM
    const u16* A = blockIdx.y ? Ah : At;
    u16*       C = blockIdx.y ? Ch : Ct;
    const int m0 = blockIdx.x * 128;     // 8 m-tiles
    const int K = HID, N = 128;

    __align__(16) __shared__ u16 As[128 * 64];
    __align__(16) __shared__ u16 Bs[128 * 64];

    const int lane = tid & 63;
    const int wid  = tid >> 6;
    const int wr   = wid >> 1;
    const int wc   = wid & 1;

    floatx4 acc[4][4] = {};

    const int srow = lane >> 3;
    const int scol = 8 * ((lane & 7) ^ (lane >> 3));
    const int cb   = wid * 4;
    const u16* Ag[4]; const u16* Bg[4];
    u16 *Al[4], *Bl[4];
#pragma unroll
    for (int j = 0; j < 4; ++j) {
        const int c = cb + j;
        const int r = c * 8 + srow;
        Ag[j] = A  + (size_t)(m0 + r) * K + scol;
        Bg[j] = BT + (size_t)r * K + scol;          // n0 = 0
        Al[j] = As + c * 512;
        Bl[j] = Bs + c * 512;
    }

    const int quad = lane >> 4;
    const int l16  = lane & 15;
    const int swz  = l16 & 7;

    for (int kt = 0; kt < (K >> 6); ++kt) {
        __syncthreads();
#pragma unroll
        for (int j = 0; j < 4; ++j) {
            gld16(Ag[j], Al[j]);  gld16(Bg[j], Bl[j]);
            Ag[j] += 64; Bg[j] += 64;
        }
        __syncthreads();

#pragma unroll
        for (int kk = 0; kk < 2; ++kk) {
            const int slot = ((kk * 4 + quad) ^ swz) * 8;
            bf16x8 af[4], bfr[4];
#pragma unroll
            for (int i = 0; i < 4; ++i) {
                af[i]  = *(const bf16x8*)(As + (wr * 64 + i * 16 + l16) * 64 + slot);
                bfr[i] = *(const bf16x8*)(Bs + (wc * 64 + i * 16 + l16) * 64 + slot);
            }
#pragma unroll
            for (int i = 0; i < 4; ++i)
#pragma unroll
                for (int j = 0; j < 4; ++j)
                    acc[i][j] = __builtin_amdgcn_mfma_f32_16x16x32_bf16(af[i], bfr[j], acc[i][j], 0, 0, 0);
        }
    }

#pragma unroll
    for (int i = 0; i < 4; ++i) {
        const int rowb = m0 + wr * 64 + i * 16 + quad * 4;
#pragma unroll
        for (int j = 0; j < 4; ++j) {
            const int col = wc * 64 + j * 16 + l16;
#pragma unroll
            for (int r = 0; r < 4; ++r)
                C[(size_t)(rowb + r) * N + col] = f2b(acc[i][j][r]);
        }
    }
}

// ---------------------------------------------------------------------------
// FUSED layer-0 stage-1: triple-gate K=128 highway kernel (proven r7).
//   h = x@Win0+bin; t = sigm(x@W't+b't); hl = tanh(x@W'h+b'h)
//   h_new = h + t*(hl - h)  (h stays fp32 in-register)
// ---------------------------------------------------------------------------
__global__ __launch_bounds__(512, 2) void gemm_hw3(
    const u16* __restrict__ A,      // [M,128] = x
    const u16* __restrict__ WtP,    // [1024,128] = (Win0@Wt00)^T
    const u16* __restrict__ WhP,    // [1024,128] = (Win0@Wh00)^T
    const u16* __restrict__ WiT,    // [1024,128] = Win0^T
    const u16* __restrict__ bpt, const u16* __restrict__ bph,
    const u16* __restrict__ bin,
    u16* __restrict__ Hout,
    int M, int N, int K)            // K = 128
{
    __align__(16) __shared__ u16 As [128 * 64];
    __align__(16) __shared__ u16 Bts[128 * 64];
    __align__(16) __shared__ u16 Bhs[128 * 64];
    __align__(16) __shared__ u16 Bis[128 * 64];

    const int tid  = threadIdx.x;
    const int lane = tid & 63;
    const int wid  = tid >> 6;          // 0..7
    const int wm   = wid >> 2;          // 0..1
    const int wn   = wid & 3;           // 0..3

    int m0, n0;
    tile_swizzle(m0, n0);

    floatx4 acct[4][2] = {};
    floatx4 acch[4][2] = {};
    floatx4 acci[4][2] = {};

    const int srow = lane >> 3;
    const int scol = 8 * ((lane & 7) ^ srow);
    const u16* Ag[2]; const u16* Tg[2]; const u16* Hg[2]; const u16* Ig[2];
    u16 *Al[2], *Tl[2], *Hl[2], *Il[2];
#pragma unroll
    for (int j = 0; j < 2; ++j) {
        const int c = wid * 2 + j;            // 0..15 (8-row chunks)
        const int r = c * 8 + srow;
        Ag[j] = A   + (size_t)(m0 + r) * K + scol;
        Tg[j] = WtP + (size_t)(n0 + r) * K + scol;
        Hg[j] = WhP + (size_t)(n0 + r) * K + scol;
        Ig[j] = WiT + (size_t)(n0 + r) * K + scol;
        Al[j] = As  + c * 512;
        Tl[j] = Bts + c * 512;
        Hl[j] = Bhs + c * 512;
        Il[j] = Bis + c * 512;
    }

    const int quad = lane >> 4;
    const int l16  = lane & 15;
    const int swz  = l16 & 7;

    const int nk = K >> 6;                    // = 2
    for (int kt = 0; kt < nk; ++kt) {
        __syncthreads();
#pragma unroll
        for (int j = 0; j < 2; ++j) {
            gld16(Ag[j], Al[j]);  gld16(Tg[j], Tl[j]);
            gld16(Hg[j], Hl[j]);  gld16(Ig[j], Il[j]);
            Ag[j] += 64; Tg[j] += 64; Hg[j] += 64; Ig[j] += 64;
        }
        __syncthreads();

#pragma unroll
        for (int kk = 0; kk < 2; ++kk) {
            const int slot = ((kk * 4 + quad) ^ swz) * 8;
            bf16x8 af[4], btf[2], bhf[2], bif[2];
#pragma unroll
            for (int i = 0; i < 4; ++i)
                af[i] = *(const bf16x8*)(As + (wm * 64 + i * 16 + l16) * 64 + slot);
#pragma unroll
            for (int j = 0; j < 2; ++j) {
                btf[j] = *(const bf16x8*)(Bts + (wn * 32 + j * 16 + l16) * 64 + slot);
                bhf[j] = *(const bf16x8*)(Bhs + (wn * 32 + j * 16 + l16) * 64 + slot);
                bif[j] = *(const bf16x8*)(Bis + (wn * 32 + j * 16 + l16) * 64 + slot);
            }
#pragma unroll
            for (int i = 0; i < 4; ++i)
#pragma unroll
                for (int j = 0; j < 2; ++j) {
                    acct[i][j] = __builtin_amdgcn_mfma_f32_16x16x32_bf16(af[i], btf[j], acct[i][j], 0, 0, 0);
                    acch[i][j] = __builtin_amdgcn_mfma_f32_16x16x32_bf16(af[i], bhf[j], acch[i][j], 0, 0, 0);
                    acci[i][j] = __builtin_amdgcn_mfma_f32_16x16x32_bf16(af[i], bif[j], acci[i][j], 0, 0, 0);
                }
        }
    }

#pragma unroll
    for (int i = 0; i < 4; ++i) {
        const int rowb = m0 + wm * 64 + i * 16 + quad * 4;
#pragma unroll
        for (int j = 0; j < 2; ++j) {
            const int col = n0 + wn * 32 + j * 16 + l16;
            const float biv = b2f(bin[col]);
            const float btv = b2f(bpt[col]);
            const float bhv = b2f(bph[col]);
#pragma unroll
            for (int r = 0; r < 4; ++r) {
                const float h  = acci[i][j][r] + biv;
                const float tg = sigm(acct[i][j][r] + btv);
                const float hl = tanh_f(acch[i][j][r] + bhv);
                Hout[(size_t)(rowb + r) * N + col] = f2b(h + tg * (hl - h));
            }
        }
    }
}

// ---------------------------------------------------------------------------
// Fused highway GEMM (proven config): BM=128, BN=128 dual-gate, BK=64,
// wave-tile 64x64, 48 KB LDS, 2 blocks/CU.
// ---------------------------------------------------------------------------
__global__ __launch_bounds__(256, 2) void gemm_hw(
    const u16* __restrict__ A,      // [M,K] = h
    const u16* __restrict__ WtT,    // [N,K]
    const u16* __restrict__ WhT,    // [N,K]
    const u16* __restrict__ bt, const u16* __restrict__ bh,
    u16* __restrict__ Hout,
    int M, int N, int K)
{
    __align__(16) __shared__ u16 As [128 * 64];
    __align__(16) __shared__ u16 Bts[128 * 64];
    __align__(16) __shared__ u16 Bhs[128 * 64];

    const int tid  = threadIdx.x;
    const int lane = tid & 63;
    const int wid  = tid >> 6;
    const int wr   = wid >> 1;
    const int wc   = wid & 1;

    int m0, n0;
    tile_swizzle(m0, n0);

    floatx4 acct[4][4] = {};
    floatx4 acch[4][4] = {};

    const int srow = lane >> 3;
    const int scol = 8 * ((lane & 7) ^ (lane >> 3));
    const int cb   = wid * 4;
    const u16* Ag[4]; const u16* Tg[4]; const u16* Hg[4];
    u16 *Al[4], *Tl[4], *Hl[4];
#pragma unroll
    for (int j = 0; j < 4; ++j) {
        const int c = cb + j;
        const int r = c * 8 + srow;
        Ag[j] = A   + (size_t)(m0 + r) * K + scol;
        Tg[j] = WtT + (size_t)(n0 + r) * K + scol;
        Hg[j] = WhT + (size_t)(n0 + r) * K + scol;
        Al[j] = As  + c * 512;
        Tl[j] = Bts + c * 512;
        Hl[j] = Bhs + c * 512;
    }

    const int quad = lane >> 4;
    const int l16  = lane & 15;
    const int swz  = l16 & 7;

    const int nk = K >> 6;
    for (int kt = 0; kt < nk; ++kt) {
        __syncthreads();
#pragma unroll
        for (int j = 0; j < 4; ++j) {
            gld16(Ag[j], Al[j]);  gld16(Tg[j], Tl[j]);  gld16(Hg[j], Hl[j]);
            Ag[j] += 64; Tg[j] += 64; Hg[j] += 64;
        }
        __syncthreads();

#pragma unroll
        for (int kk = 0; kk < 2; ++kk) {
            const int slot = ((kk * 4 + quad) ^ swz) * 8;
            bf16x8 af[4], btf[4], bhf[4];
#pragma unroll
            for (int i = 0; i < 4; ++i) {
                af[i]  = *(const bf16x8*)(As  + (wr * 64 + i * 16 + l16) * 64 + slot);
                btf[i] = *(const bf16x8*)(Bts + (wc * 64 + i * 16 + l16) * 64 + slot);
                bhf[i] = *(const bf16x8*)(Bhs + (wc * 64 + i * 16 + l16) * 64 + slot);
            }
#pragma unroll
            for (int i = 0; i < 4; ++i)
#pragma unroll
                for (int j = 0; j < 4; ++j) {
                    acct[i][j] = __builtin_amdgcn_mfma_f32_16x16x32_bf16(af[i], btf[j], acct[i][j], 0, 0, 0);
                    acch[i][j] = __builtin_amdgcn_mfma_f32_16x16x32_bf16(af[i], bhf[j], acch[i][j], 0, 0, 0);
                }
        }
    }

#pragma unroll
    for (int i = 0; i < 4; ++i) {
        const int rowb = m0 + wr * 64 + i * 16 + quad * 4;
#pragma unroll
        for (int j = 0; j < 4; ++j) {
            const int col = n0 + wc * 64 + j * 16 + l16;
            const float btv = b2f(bt[col]);
            const float bhv = b2f(bh[col]);
#pragma unroll
            for (int r = 0; r < 4; ++r) {
                const size_t idx = (size_t)(rowb + r) * N + col;
                const float hold = b2f(A[idx]);
                const float tg = sigm(acct[i][j][r] + btv);
                const float hl = tanh_f(acch[i][j][r] + bhv);
                Hout[idx] = f2b(hold + tg * (hl - hold));
            }
        }
    }
}

// ---------------------------------------------------------------------------
// Final-stage highway GEMM (proven config): identical K-loop; epilogue
// reduces h_new over the tile's 128 rows and writes NON-ATOMIC partials into
// hpart[slot][b][col], slot = mtile_parity*2 + wr.
// ---------------------------------------------------------------------------
__global__ __launch_bounds__(256, 2) void gemm_hw_sum(
    const u16* __restrict__ A,      // [M,K] = h
    const u16* __restrict__ WtT,    // [N,K]
    const u16* __restrict__ WhT,    // [N,K]
    const u16* __restrict__ bt, const u16* __restrict__ bh,
    float* __restrict__ hpart,      // [4, BATCH, HID] fp32 partials
    int M, int N, int K)
{
    __align__(16) __shared__ u16 As [128 * 64];
    __align__(16) __shared__ u16 Bts[128 * 64];
    __align__(16) __shared__ u16 Bhs[128 * 64];

    const int tid  = threadIdx.x;
    const int lane = tid & 63;
    const int wid  = tid >> 6;
    const int wr   = wid >> 1;
    const int wc   = wid & 1;

    int m0, n0;
    tile_swizzle(m0, n0);

    floatx4 acct[4][4] = {};
    floatx4 acch[4][4] = {};

    const int srow = lane >> 3;
    const int scol = 8 * ((lane & 7) ^ (lane >> 3));
    const int cb   = wid * 4;
    const u16* Ag[4]; const u16* Tg[4]; const u16* Hg[4];
    u16 *Al[4], *Tl[4], *Hl[4];
#pragma unroll
    for (int j = 0; j < 4; ++j) {
        const int c = cb + j;
        const int r = c * 8 + srow;
        Ag[j] = A   + (size_t)(m0 + r) * K + scol;
        Tg[j] = WtT + (size_t)(n0 + r) * K + scol;
        Hg[j] = WhT + (size_t)(n0 + r) * K + scol;
        Al[j] = As  + c * 512;
        Tl[j] = Bts + c * 512;
        Hl[j] = Bhs + c * 512;
    }

    const int quad = lane >> 4;
    const int l16  = lane & 15;
    const int swz  = l16 & 7;

    const int nk = K >> 6;
    for (int kt = 0; kt < nk; ++kt) {
        __syncthreads();
#pragma unroll
        for (int j = 0; j < 4; ++j) {
            gld16(Ag[j], Al[j]);  gld16(Tg[j], Tl[j]);  gld16(Hg[j], Hl[j]);
            Ag[j] += 64; Tg[j] += 64; Hg[j] += 64;
        }
        __syncthreads();

#pragma unroll
        for (int kk = 0; kk < 2; ++kk) {
            const int slot = ((kk * 4 + quad) ^ swz) * 8;
            bf16x8 af[4], btf[4], bhf[4];
#pragma unroll
            for (int i = 0; i < 4; ++i) {
                af[i]  = *(const bf16x8*)(As  + (wr * 64 + i * 16 + l16) * 64 + slot);
                btf[i] = *(const bf16x8*)(Bts + (wc * 64 + i * 16 + l16) * 64 + slot);
                bhf[i] = *(const bf16x8*)(Bhs + (wc * 64 + i * 16 + l16) * 64 + slot);
            }
#pragma unroll
            for (int i = 0; i < 4; ++i)
#pragma unroll
                for (int j = 0; j < 4; ++j) {
                    acct[i][j] = __builtin_amdgcn_mfma_f32_16x16x32_bf16(af[i], btf[j], acct[i][j], 0, 0, 0);
                    acch[i][j] = __builtin_amdgcn_mfma_f32_16x16x32_bf16(af[i], bhf[j], acch[i][j], 0, 0, 0);
                }
        }
    }

    const int b    = m0 >> 8;
    const int slot = ((m0 >> 7) & 1) * 2 + wr;
#pragma unroll
    for (int j = 0; j < 4; ++j) {
        const int col = n0 + wc * 64 + j * 16 + l16;
        const float btv = b2f(bt[col]);
        const float bhv = b2f(bh[col]);
        float colsum = 0.f;
#pragma unroll
        for (int i = 0; i < 4; ++i) {
            const int rowb = m0 + wr * 64 + i * 16 + quad * 4;
#pragma unroll
            for (int r = 0; r < 4; ++r) {
                const size_t idx = (size_t)(rowb + r) * N + col;
                const float hold = b2f(A[idx]);
                const float tg = sigm(acct[i][j][r] + btv);
                const float hl = tanh_f(acch[i][j][r] + bhv);
                colsum += hold + tg * (hl - hold);
            }
        }
        colsum += __shfl_xor(colsum, 16, 64);
        colsum += __shfl_xor(colsum, 32, 64);
        if (quad == 0)
            hpart[((size_t)(slot * BATCH + b)) * HID + col] = colsum;
    }
}

// ---------------------------------------------------------------------------
// 8-wave pipelined dual-gate highway K-loop (counted-vmcnt schedule — the
// PROVEN 92.5 µs cum mainloop): BM=256, BN=128, BK=64, 512 thr,
// LDS = 2 x (A 32K | Bt 16K | Bh 16K) = 128 KiB double-buffered.
// ---------------------------------------------------------------------------
__device__ __forceinline__ void hw8_mainloop(
    u16* lds,
    const u16* __restrict__ A, const u16* __restrict__ WtT, const u16* __restrict__ WhT,
    int m0, int n0, int K,
    floatx4 (&acct)[4][4], floatx4 (&acch)[4][4])
{
    const int tid  = threadIdx.x;
    const int lane = tid & 63;
    const int wid  = tid >> 6;          // 0..7
    const int wr   = wid >> 1;          // 0..3
    const int wc   = wid & 1;

    const int srow = lane >> 3;
    const int scol = 8 * ((lane & 7) ^ srow);

    const u16* Ag = A   + (size_t)(m0 + wid * 32 + srow) * K + scol;
    const u16* Tg = WtT + (size_t)(n0 + wid * 16 + srow) * K + scol;
    const u16* Hg = WhT + (size_t)(n0 + wid * 16 + srow) * K + scol;
    const size_t K8 = (size_t)K * 8;

    u16* dA = lds + wid * 2048;
    u16* dT = lds + 16384 + wid * 1024;
    u16* dH = lds + 24576 + wid * 1024;

    const int quad = lane >> 4;
    const int l16  = lane & 15;
    const int swz  = l16 & 7;
    const int s0 = (quad ^ swz) * 8;
    const int s1 = ((4 + quad) ^ swz) * 8;
    const int ra = wr * 64 + l16;
    const int rb = wc * 64 + l16;

    gld16(Tg,           dT);
    gld16(Tg +     K8,  dT + 512);
    gld16(Ag,           dA);
    gld16(Ag +     K8,  dA + 512);
    gld16(Ag + 2 * K8,  dA + 1024);
    gld16(Ag + 3 * K8,  dA + 1536);
    gld16(Hg,           dH);
    gld16(Hg +     K8,  dH + 512);
    Ag += 64; Tg += 64; Hg += 64;
    vm_bar<2>();                               // T+A of tile 0 ready; H in flight

    const int nk = K >> 6;
    for (int kt = 0; kt < nk; ++kt) {
        const int  cur = kt & 1;
        const int  nb  = (cur ^ 1) * 32768;
        const bool pf  = (kt + 1 < nk);
        const u16* Sa = lds + cur * 32768;
        const u16* St = Sa + 16384;
        const u16* Sh = Sa + 24576;

        bf16x8 af0[4], af1[4], bq[4];

        // ---- P0: T-gate kk0 ----
#pragma unroll
        for (int i = 0; i < 4; ++i) {
            af0[i] = *(const bf16x8*)(Sa + (ra + i * 16) * 64 + s0);
            bq[i]  = *(const bf16x8*)(St + (rb + i * 16) * 64 + s0);
        }
        if (pf) {
            gld16(Tg,      dT + nb);  gld16(Tg + K8, dT + nb + 512);
            gld16(Ag,      dA + nb);  gld16(Ag + K8, dA + nb + 512);
        }
        bar_sync();
        __builtin_amdgcn_s_setprio(1);
#pragma unroll
        for (int i = 0; i < 4; ++i)
#pragma unroll
            for (int j = 0; j < 4; ++j)
                acct[i][j] = __builtin_amdgcn_mfma_f32_16x16x32_bf16(af0[i], bq[j], acct[i][j], 0, 0, 0);
        __builtin_amdgcn_s_setprio(0);

        // ---- P1: T-gate kk1 ----
#pragma unroll
        for (int i = 0; i < 4; ++i) {
            af1[i] = *(const bf16x8*)(Sa + (ra + i * 16) * 64 + s1);
            bq[i]  = *(const bf16x8*)(St + (rb + i * 16) * 64 + s1);
        }
        if (pf) {
            gld16(Ag + 2 * K8, dA + nb + 1024);
            gld16(Ag + 3 * K8, dA + nb + 1536);
            vm_bar<6>();                       // forces H(kt); 6 newer stay in flight
        } else {
            vm_bar<0>();                       // last tile: full drain
        }
        __builtin_amdgcn_s_setprio(1);
#pragma unroll
        for (int i = 0; i < 4; ++i)
#pragma unroll
            for (int j = 0; j < 4; ++j)
                acct[i][j] = __builtin_amdgcn_mfma_f32_16x16x32_bf16(af1[i], bq[j], acct[i][j], 0, 0, 0);
        __builtin_amdgcn_s_setprio(0);

        // ---- P2: H-gate kk0 ----
#pragma unroll
        for (int i = 0; i < 4; ++i)
            bq[i] = *(const bf16x8*)(Sh + (rb + i * 16) * 64 + s0);
        bar_sync();
        __builtin_amdgcn_s_setprio(1);
#pragma unroll
        for (int i = 0; i < 4; ++i)
#pragma unroll
            for (int j = 0; j < 4; ++j)
                acch[i][j] = __builtin_amdgcn_mfma_f32_16x16x32_bf16(af0[i], bq[j], acch[i][j], 0, 0, 0);
        __builtin_amdgcn_s_setprio(0);

        // ---- P3: H-gate kk1 ----
#pragma unroll
        for (int i = 0; i < 4; ++i)
            bq[i] = *(const bf16x8*)(Sh + (rb + i * 16) * 64 + s1);
        if (pf) {
            gld16(Hg,      dH + nb);
            gld16(Hg + K8, dH + nb + 512);
            vm_bar<2>();                       // forces T+A(kt+1); H(kt+1) in flight
        } else {
            bar_sync();
        }
        __builtin_amdgcn_s_setprio(1);
#pragma unroll
        for (int i = 0; i < 4; ++i)
#pragma unroll
            for (int j = 0; j < 4; ++j)
                acch[i][j] = __builtin_amdgcn_mfma_f32_16x16x32_bf16(af1[i], bq[j], acch[i][j], 0, 0, 0);
        __builtin_amdgcn_s_setprio(0);

        Ag += 64; Tg += 64; Hg += 64;
    }
}

// ---------------------------------------------------------------------------
// Layer-0 stage-2 highway GEMM with FUSED cumsum-over-t (proven: 92.5 µs).
// BM=256 == SEQ: each block owns one full batch's 256 timesteps x 128 cols.
// ---------------------------------------------------------------------------
__global__ __launch_bounds__(512, 2) void gemm_hw8_cum(
    const u16* __restrict__ A,      // [M,K] = h
    const u16* __restrict__ WtT,    // [N,K]
    const u16* __restrict__ WhT,    // [N,K]
    const u16* __restrict__ bt, const u16* __restrict__ bh,
    u16* __restrict__ Y,            // [M,N] y0 = cumsum_t(h_new)
    int M, int N, int K)
{
    __align__(16) __shared__ u16 lds[65536];   // 128 KiB (mainloop), reused below
    __shared__ float tot[512];

    int m0, n0;
    tile_swizzle8(m0, n0);

    floatx4 acct[4][4] = {};
    floatx4 acch[4][4] = {};
    hw8_mainloop(lds, A, WtT, WhT, m0, n0, K, acct, acch);

    const int tid  = threadIdx.x;
    const int lane = tid & 63;
    const int wid  = tid >> 6;
    const int wr   = wid >> 1;
    const int wc   = wid & 1;
    const int quad = lane >> 4;
    const int l16  = lane & 15;

    __syncthreads();   // drain per-wave LDS ops before buffer reuse

    // stage h_new (bf16) into lds[row][col] with padded stride CUMP
#pragma unroll
    for (int i = 0; i < 4; ++i) {
        const int rowl = wr * 64 + i * 16 + quad * 4;
#pragma unroll
        for (int j = 0; j < 4; ++j) {
            const int coll = wc * 64 + j * 16 + l16;
            const float btv = b2f(bt[n0 + coll]);
            const float bhv = b2f(bh[n0 + coll]);
#pragma unroll
            for (int r = 0; r < 4; ++r) {
                const size_t idx = (size_t)(m0 + rowl + r) * N + n0 + coll;
                const float hold = b2f(A[idx]);
                const float tg = sigm(acct[i][j][r] + btv);
                const float hl = tanh_f(acch[i][j][r] + bhv);
                lds[(rowl + r) * CUMP + coll] = f2b(hold + tg * (hl - hold));
            }
        }
    }
    __syncthreads();

    // segmented scan: seg = tid>>7 (64 t's each), col = tid&127
    const int seg  = tid >> 7;
    const int colc = tid & 127;
    const int base = seg * 64 * CUMP + colc;
    {
        float local = 0.f;
#pragma unroll 8
        for (int t = 0; t < 64; ++t)
            local += b2f(lds[base + t * CUMP]);
        tot[seg * 128 + colc] = local;
    }
    __syncthreads();
    {
        float off = 0.f;
#pragma unroll
        for (int s = 0; s < 3; ++s)
            off += (s < seg) ? tot[s * 128 + colc] : 0.f;
        float acc = off;
#pragma unroll 8
        for (int t = 0; t < 64; ++t) {
            const int o = base + t * CUMP;
            acc += b2f(lds[o]);
            lds[o] = f2b(acc);
        }
    }
    __syncthreads();

    // coalesced tile write: 16 iters x 512 thr x 4 u16 = 256x128
#pragma unroll
    for (int it = 0; it < 16; ++it) {
        const int o   = it * 2048 + tid * 4;
        const int row = o >> 7;
        const int col = o & 127;
        *(uint2*)&Y[(size_t)(m0 + row) * N + n0 + col] =
            *(const uint2*)&lds[row * CUMP + col];
    }
}

// final fc: sums the 4 hpart slots; self-detected dtype on W/bias and output
__global__ void fc_final(const float* __restrict__ hp, const void* __restrict__ W,
                         const void* __restrict__ bias, void* __restrict__ out) {
    __shared__ float sh[HID];
    const int fp32 = is_fp32((const u16*)W, threadIdx.x);
    const int b = blockIdx.x, o = threadIdx.x;      // 64 blocks x 128 threads
    for (int k = o; k < HID; k += 128) {
        float v = 0.f;
#pragma unroll
        for (int s = 0; s < 4; ++s)
            v += hp[((size_t)(s * BATCH + b)) * HID + k];
        sh[k] = v;
    }
    __syncthreads();
    float acc;
    if (fp32) {
        acc = ((const float*)bias)[o];
        for (int k = 0; k < HID; ++k)
            acc += sh[k] * ((const float*)W)[(size_t)k * OUTDIM + o];
        ((float*)out)[b * OUTDIM + o] = acc;
    } else {
        acc = b2f(((const u16*)bias)[o]);
        for (int k = 0; k < HID; ++k)
            acc += sh[k] * b2f(((const u16*)W)[(size_t)k * OUTDIM + o]);
        ((u16*)out)[b * OUTDIM + o] = f2b(acc);
    }
}

// ---------------------------------------------------------------------------
extern "C" void kernel_launch(void* const* d_in, const int* in_sizes, int n_in,
                              void* d_out, int out_size, void* d_ws, size_t ws_size,
                              hipStream_t stream) {
    const void* x      = d_in[0];
    const void* l0_Win = d_in[1];
    const void* l0_bin = d_in[2];
    const void* l0_Wh  = d_in[3];
    const void* l0_bh  = d_in[4];
    const void* l0_Wt  = d_in[5];
    const void* l0_bt  = d_in[6];
    const void* l1_Win = d_in[7];
    const void* l1_bin = d_in[8];
    const void* l1_Wh  = d_in[9];
    const void* l1_bh  = d_in[10];
    const void* l1_Wt  = d_in[11];
    const void* l1_bt  = d_in[12];
    const void* fc_W   = d_in[13];
    const void* fc_b   = d_in[14];

    char* ws = (char*)d_ws;
    u16* Pa = (u16*)(ws);                       // 32 MB
    u16* Pb = (u16*)(ws + 33554432);            // 32 MB; xc at its base
    u16* xc = Pb;                               // [16384,128] clean bf16 x
    u16* tW = (u16*)(ws + 67108864);
    u16* tWin0 = tW;                  // [1024,128]
    u16* tWt00 = tWin0 + 131072;      // each [1024,1024]
    u16* tWt01 = tWt00 + 1048576;
    u16* tWh00 = tWt01 + 1048576;
    u16* tWh01 = tWh00 + 1048576;
    u16* tWin1 = tWh01 + 1048576;
    u16* tWt10 = tWin1 + 1048576;
    u16* tWt11 = tWt10 + 1048576;
    u16* tWh10 = tWt11 + 1048576;
    u16* tWh11 = tWh10 + 1048576;
    u16* smallb = tWh11 + 1048576;    // bias copies
    u16* binc0 = smallb;              // 1024
    u16* bhc0  = binc0 + 1024;        // 2048
    u16* btc0  = bhc0 + 2048;         // 2048
    u16* binc1 = btc0 + 2048;         // 1024
    u16* bhc1  = binc1 + 1024;        // 2048
    u16* btc1  = bhc1 + 2048;         // 2048
    u16* Win0c = btc1 + 2048;         // [128,1024] clean orig-orientation Win0
    u16* Wpt   = Win0c + 131072;      // [1024,128] = (Win0@Wt00)^T
    u16* Wph   = Wpt + 131072;        // [1024,128] = (Win0@Wh00)^T
    u16* bpt   = Wph + 131072;        // [1024] folded t-bias
    u16* bph   = bpt + 1024;          // [1024] folded h-bias
    float* hpart = (float*)Pa;        // [4,64,1024] fp32 partials; Pa dead at tail

    const u16* probe = (const u16*)l0_Wh;   // dtype probe tensor

    const long DD = (long)HID * HID;
    PrepList P;
    P.ts[0] = l0_Win; P.td[0] = tWin0; P.tR[0] = INDIM; P.tC[0] = HID; P.toff[0] = 0;
    P.ts[1] = l0_Wt;  P.td[1] = tWt00; P.tR[1] = HID;   P.tC[1] = HID; P.toff[1] = 0;
    P.ts[2] = l0_Wt;  P.td[2] = tWt01; P.tR[2] = HID;   P.tC[2] = HID; P.toff[2] = DD;
    P.ts[3] = l0_Wh;  P.td[3] = tWh00; P.tR[3] = HID;   P.tC[3] = HID; P.toff[3] = 0;
    P.ts[4] = l0_Wh;  P.td[4] = tWh01; P.tR[4] = HID;   P.tC[4] = HID; P.toff[4] = DD;
    P.ts[5] = l1_Win; P.td[5] = tWin1; P.tR[5] = HID;   P.tC[5] = HID; P.toff[5] = 0;
    P.ts[6] = l1_Wt;  P.td[6] = tWt10; P.tR[6] = HID;   P.tC[6] = HID; P.toff[6] = 0;
    P.ts[7] = l1_Wt;  P.td[7] = tWt11; P.tR[7] = HID;   P.tC[7] = HID; P.toff[7] = DD;
    P.ts[8] = l1_Wh;  P.td[8] = tWh10; P.tR[8] = HID;   P.tC[8] = HID; P.toff[8] = 0;
    P.ts[9] = l1_Wh;  P.td[9] = tWh11; P.tR[9] = HID;   P.tC[9] = HID; P.toff[9] = DD;
    P.cs[0] = x;      P.cd[0] = xc;    P.cn[0] = MROWS * INDIM;
    P.cs[1] = l0_bin; P.cd[1] = binc0; P.cn[1] = HID;
    P.cs[2] = l0_bh;  P.cd[2] = bhc0;  P.cn[2] = 2 * HID;
    P.cs[3] = l0_bt;  P.cd[3] = btc0;  P.cn[3] = 2 * HID;
    P.cs[4] = l1_bin; P.cd[4] = binc1; P.cn[4] = HID;
    P.cs[5] = l1_bh;  P.cd[5] = bhc1;  P.cn[5] = 2 * HID;
    P.cs[6] = l1_bt;  P.cd[6] = btc1;  P.cn[6] = 2 * HID;
    P.cs[7] = l0_Win; P.cd[7] = Win0c; P.cn[7] = INDIM * HID;
    prep18<<<dim3(32, 32, 18), 256, 0, stream>>>(P, probe);

    // ---- layer-0 weight folding + bias fold (one launch) ----
    gemm_wp_bias<<<dim3(8, 2, 2), 256, 0, stream>>>(tWt00, tWh00, Win0c,
                                                    binc0, btc0, bhc0,
                                                    Wpt, Wph, bpt, bph);

    // ---- layer 0 ----
    // stage 1: fused triple-gate K=128 (replaces gemm128 + gemm_hw)
    gemm_hw3<<<dim3(8, 128), 512, 0, stream>>>(xc, Wpt, Wph, tWin0, bpt, bph, binc0,
                                               Pa, MROWS, HID, INDIM);
    // stage 2 with fused cumsum-over-t -> Pb = y0
    gemm_hw8_cum<<<512, 512, 0, stream>>>(Pa, tWt01, tWh01, btc0 + HID, bhc0 + HID, Pb, MROWS, HID, HID);

    // ---- layer 1 ----
    gemm128<<<dim3(8, 128), 256, 0, stream>>>(Pb, tWin1, binc1, Pa, MROWS, HID, HID);
    gemm_hw<<<dim3(8, 128), 256, 0, stream>>>(Pa, tWt10, tWh10, btc1, bhc1, Pb, MROWS, HID, HID);
    // final depth stage: non-atomic partial sums into hpart (Pa dead)
    gemm_hw_sum<<<dim3(8, 128), 256, 0, stream>>>(Pb, tWt11, tWh11, btc1 + HID, bhc1 + HID,
                                                  hpart, MROWS, HID, HID);

    // ---- tail ----
    fc_final<<<64, 128, 0, stream>>>(hpart, fc_W, fc_b, d_out);
}